// Round 3
// baseline (170.655 us; speedup 1.0000x reference)
//
#include <hip/hip_runtime.h>
#include <hip/hip_bf16.h>

typedef unsigned short u16;
typedef __attribute__((ext_vector_type(4))) float f32x4;
typedef __attribute__((ext_vector_type(8))) short bf16x8;

#define IN_F   4096
#define OUT_F  4096
#define BATCH  512

#define BM 64
#define BN 128
#define BK 64
#define NSTEPS (IN_F / BK)   // 64
#define DEPTH 4              // LDS ring buffers, prefetch distance 3

__device__ inline u16 f2bf(float f) {
    __hip_bfloat16 h = __float2bfloat16(f);   // RNE
    u16 u; __builtin_memcpy(&u, &h, 2); return u;
}

// Pass 1: last-write-wins index resolution. aux pre-set to -1 (memset 0xFF).
__global__ __launch_bounds__(256) void scatter_max(const int* __restrict__ row,
                                                   const int* __restrict__ col,
                                                   int* __restrict__ aux, int nnz) {
    int t = blockIdx.x * 256 + threadIdx.x;
    int base = t * 8;
    if (base + 8 <= nnz) {
#pragma unroll
        for (int j = 0; j < 2; j++) {
            int4 r = ((const int4*)row)[t * 2 + j];
            int4 c = ((const int4*)col)[t * 2 + j];
            int i0 = base + j * 4;
            atomicMax(&aux[r.x * IN_F + c.x], i0 + 0);
            atomicMax(&aux[r.y * IN_F + c.y], i0 + 1);
            atomicMax(&aux[r.z * IN_F + c.z], i0 + 2);
            atomicMax(&aux[r.w * IN_F + c.w], i0 + 3);
        }
    } else if (base < nnz) {
        for (int i = base; i < nnz; i++)
            atomicMax(&aux[row[i] * IN_F + col[i]], i);
    }
}

// Pass 2: build dense bf16 W (zero-fill fused with scatter resolution).
__global__ __launch_bounds__(256) void fill_w(const int* __restrict__ aux,
                                              const float* __restrict__ w,
                                              u16* __restrict__ Wbf) {
    int i = blockIdx.x * 256 + threadIdx.x;   // handles 4 positions
    int4 a = ((const int4*)aux)[i];
    ushort4 o;
    o.x = a.x >= 0 ? f2bf(w[a.x]) : (u16)0;
    o.y = a.y >= 0 ? f2bf(w[a.y]) : (u16)0;
    o.z = a.z >= 0 ? f2bf(w[a.z]) : (u16)0;
    o.w = a.w >= 0 ? f2bf(w[a.w]) : (u16)0;
    ((ushort4*)Wbf)[i] = o;
}

__global__ __launch_bounds__(256) void conv_x(const float* __restrict__ x,
                                              u16* __restrict__ xbf) {
    int i = blockIdx.x * 256 + threadIdx.x;   // handles 4 elements
    float4 v = ((const float4*)x)[i];
    ushort4 o;
    o.x = f2bf(v.x); o.y = f2bf(v.y); o.z = f2bf(v.z); o.w = f2bf(v.w);
    ((ushort4*)xbf)[i] = o;
}

// C[m][n] = sum_k A[m][k]*B[n][k] + bias[n].
// 1 block/CU, 4-deep LDS ring, counted vmcnt (never drained mid-loop),
// LDS 16B-block XOR swizzle applied on the GLOBAL SOURCE side (linear
// global_load_lds dest) and mirrored on the ds_read side.
__global__ __launch_bounds__(256) void gemm_bias(const u16* __restrict__ A,
                                                 const u16* __restrict__ B,
                                                 const float* __restrict__ bias,
                                                 float* __restrict__ C) {
    __shared__ u16 As[DEPTH][BM * BK];   // 4 x 8 KB
    __shared__ u16 Bs[DEPTH][BN * BK];   // 4 x 16 KB  => 96 KB total
    const int L  = blockIdx.x;
    const int m0 = (L >> 5) * BM;        // 8 M-blocks
    const int n0 = (L & 31) * BN;        // 32 N-blocks; L%8==n%8 -> same-n blocks share an XCD
    const int tid  = threadIdx.x;
    const int lane = tid & 63;
    const int wave = tid >> 6;
    const int wm = wave >> 1, wn = wave & 1;   // 2x2 waves, wave tile 32x64
    const int r15 = lane & 15, khi = lane >> 4;

    // Pre-swizzled per-thread staging sources. LDS slot (row, lblk) holds
    // global 16B block gblk = lblk ^ (row&7).  (o is 16B-aligned: o&15==0)
    const u16* srcA[2]; int dstA[2];
    const u16* srcB[4]; int dstB[4];
#pragma unroll
    for (int it = 0; it < 2; it++) {
        int o = tid * 16 + it * 4096;
        int rr = o >> 7, lblk = (o >> 4) & 7;
        srcA[it] = A + (size_t)(m0 + rr) * IN_F + ((lblk ^ (rr & 7)) << 3);
        dstA[it] = o >> 1;
    }
#pragma unroll
    for (int it = 0; it < 4; it++) {
        int o = tid * 16 + it * 4096;
        int rr = o >> 7, lblk = (o >> 4) & 7;
        srcB[it] = B + (size_t)(n0 + rr) * IN_F + ((lblk ^ (rr & 7)) << 3);
        dstB[it] = o >> 1;
    }

#define STAGE(slot, kt)                                                              \
    do {                                                                             \
        _Pragma("unroll")                                                            \
        for (int it = 0; it < 2; it++)                                               \
            __builtin_amdgcn_global_load_lds(                                        \
                (const __attribute__((address_space(1))) void*)(srcA[it] + (kt)),    \
                (__attribute__((address_space(3))) void*)(&As[slot][dstA[it]]),      \
                16, 0, 0);                                                           \
        _Pragma("unroll")                                                            \
        for (int it = 0; it < 4; it++)                                               \
            __builtin_amdgcn_global_load_lds(                                        \
                (const __attribute__((address_space(1))) void*)(srcB[it] + (kt)),    \
                (__attribute__((address_space(3))) void*)(&Bs[slot][dstB[it]]),      \
                16, 0, 0);                                                           \
    } while (0)

    f32x4 acc[2][4];
#pragma unroll
    for (int mi = 0; mi < 2; mi++)
#pragma unroll
        for (int nj = 0; nj < 4; nj++) acc[mi][nj] = (f32x4){0.f, 0.f, 0.f, 0.f};

    STAGE(0, 0); STAGE(1, BK); STAGE(2, 2 * BK);   // 18 loads/wave outstanding

    for (int t = 0; t < NSTEPS; ++t) {
        // oldest 6 loads (this slot) must have landed; keep 12 in flight
        if (t < NSTEPS - 2)       asm volatile("s_waitcnt vmcnt(12)" ::: "memory");
        else if (t == NSTEPS - 2) asm volatile("s_waitcnt vmcnt(6)"  ::: "memory");
        else                      asm volatile("s_waitcnt vmcnt(0)"  ::: "memory");
        __builtin_amdgcn_s_barrier();
        __builtin_amdgcn_sched_barrier(0);
        if (t + 3 < NSTEPS) STAGE((t + 3) & 3, (t + 3) * BK);

        const char* as = (const char*)&As[t & 3][0];
        const char* bs = (const char*)&Bs[t & 3][0];
#pragma unroll
        for (int ks = 0; ks < 2; ks++) {
            bf16x8 a[2], b[4];
#pragma unroll
            for (int mi = 0; mi < 2; mi++) {
                int row = wm * 32 + mi * 16 + r15;
                a[mi] = *(const bf16x8*)(as + row * 128 + (((ks * 4 + khi) ^ (row & 7)) << 4));
            }
#pragma unroll
            for (int nj = 0; nj < 4; nj++) {
                int row = wn * 64 + nj * 16 + r15;
                b[nj] = *(const bf16x8*)(bs + row * 128 + (((ks * 4 + khi) ^ (row & 7)) << 4));
            }
#pragma unroll
            for (int mi = 0; mi < 2; mi++)
#pragma unroll
                for (int nj = 0; nj < 4; nj++)
                    acc[mi][nj] = __builtin_amdgcn_mfma_f32_16x16x32_bf16(a[mi], b[nj], acc[mi][nj], 0, 0, 0);
        }
    }
#undef STAGE

    // epilogue: D layout col=lane&15, row=(lane>>4)*4+j; bias fused
#pragma unroll
    for (int nj = 0; nj < 4; nj++) {
        int colg = n0 + wn * 64 + nj * 16 + r15;
        float bv = bias[colg];
#pragma unroll
        for (int mi = 0; mi < 2; mi++) {
#pragma unroll
            for (int j = 0; j < 4; j++) {
                int rowg = m0 + wm * 32 + mi * 16 + khi * 4 + j;
                C[(size_t)rowg * OUT_F + colg] = acc[mi][nj][j] + bv;
            }
        }
    }
}

extern "C" void kernel_launch(void* const* d_in, const int* in_sizes, int n_in,
                              void* d_out, int out_size, void* d_ws, size_t ws_size,
                              hipStream_t stream) {
    const float* x    = (const float*)d_in[0];
    const float* w1d  = (const float*)d_in[1];
    const float* bias = (const float*)d_in[2];
    const int*   row  = (const int*)d_in[3];
    const int*   col  = (const int*)d_in[4];
    const int nnz = in_sizes[1];

    char* ws  = (char*)d_ws;
    int*  aux = (int*)ws;                               // 64 MB
    u16*  Wbf = (u16*)(ws + ((size_t)64 << 20));        // 32 MB
    u16*  xbf = (u16*)(ws + ((size_t)96 << 20));        // 4 MB
    float* y  = (float*)d_out;

    conv_x<<<(BATCH * IN_F / 4) / 256, 256, 0, stream>>>(x, xbf);
    hipMemsetAsync(aux, 0xFF, (size_t)OUT_F * IN_F * sizeof(int), stream);  // aux = -1
    int sthreads = (nnz + 7) / 8;
    scatter_max<<<(sthreads + 255) / 256, 256, 0, stream>>>(row, col, aux, nnz);
    fill_w<<<(OUT_F * IN_F / 4) / 256, 256, 0, stream>>>(aux, w1d, Wbf);
    gemm_bias<<<8 * 32, 256, 0, stream>>>(xbf, Wbf, bias, y);
}